// Round 1
// baseline (10403.413 us; speedup 1.0000x reference)
//
#include <hip/hip_runtime.h>

#define TSTEPS 2000
#define NBATCH 16
#define DDIM   512
#define HDIM   512
#define MTOT   (NBATCH * TSTEPS)
#define LEPS   1e-5f

// ---------------- Phase 1: w = BN(x @ W^T) ----------------
// a-part (gates 0..511)   -> d_out   (read then overwritten by h in phase 2)
// z-part (gates 512..1023)-> d_ws
__global__ __launch_bounds__(256) void gemm_bn_kernel(
    const float* __restrict__ x, const float* __restrict__ W,
    const float* __restrict__ gamma, const float* __restrict__ beta,
    const float* __restrict__ rmean, const float* __restrict__ rvar,
    float* __restrict__ out_a, float* __restrict__ out_z)
{
  __shared__ float As[64][36];   // [m][k], +4 pad keeps float4 alignment
  __shared__ float Bs[64][36];   // [g][k]
  const int tid = threadIdx.x;
  const int m0 = blockIdx.y * 64;
  const int n0 = blockIdx.x * 64;
  const int tx = tid & 15, ty = tid >> 4;
  const int lrow = tid >> 3;          // 0..31
  const int lk = (tid & 7) * 4;       // 0..28
  float acc[4][4];
#pragma unroll
  for (int i = 0; i < 4; ++i)
#pragma unroll
    for (int j = 0; j < 4; ++j) acc[i][j] = 0.f;

  for (int k0 = 0; k0 < DDIM; k0 += 32) {
    float4 x0 = *(const float4*)&x[(size_t)(m0 + lrow) * DDIM + k0 + lk];
    float4 x1 = *(const float4*)&x[(size_t)(m0 + 32 + lrow) * DDIM + k0 + lk];
    float4 w0 = *(const float4*)&W[(size_t)(n0 + lrow) * DDIM + k0 + lk];
    float4 w1 = *(const float4*)&W[(size_t)(n0 + 32 + lrow) * DDIM + k0 + lk];
    __syncthreads();
    *(float4*)&As[lrow][lk]      = x0;
    *(float4*)&As[32 + lrow][lk] = x1;
    *(float4*)&Bs[lrow][lk]      = w0;
    *(float4*)&Bs[32 + lrow][lk] = w1;
    __syncthreads();
#pragma unroll
    for (int kk = 0; kk < 32; kk += 4) {
      float4 av[4], bv[4];
#pragma unroll
      for (int i = 0; i < 4; ++i) av[i] = *(const float4*)&As[ty * 4 + i][kk];
#pragma unroll
      for (int j = 0; j < 4; ++j) bv[j] = *(const float4*)&Bs[tx * 4 + j][kk];
#pragma unroll
      for (int i = 0; i < 4; ++i)
#pragma unroll
        for (int j = 0; j < 4; ++j)
          acc[i][j] += av[i].x * bv[j].x + av[i].y * bv[j].y +
                       av[i].z * bv[j].z + av[i].w * bv[j].w;
    }
  }

  const int gg0 = n0 + tx * 4;
  float4 gm = *(const float4*)&gamma[gg0];
  float4 bt = *(const float4*)&beta[gg0];
  float4 mn = *(const float4*)&rmean[gg0];
  float4 vr = *(const float4*)&rvar[gg0];
  const float inv0 = gm.x * rsqrtf(vr.x + LEPS);
  const float inv1 = gm.y * rsqrtf(vr.y + LEPS);
  const float inv2 = gm.z * rsqrtf(vr.z + LEPS);
  const float inv3 = gm.w * rsqrtf(vr.w + LEPS);
  float* dstb = (gg0 < HDIM) ? out_a : out_z;     // uniform per block (64 | 512)
  const int col = (gg0 < HDIM) ? gg0 : gg0 - HDIM;
#pragma unroll
  for (int i = 0; i < 4; ++i) {
    const int row = m0 + ty * 4 + i;
    float4 r;
    r.x = (acc[i][0] - mn.x) * inv0 + bt.x;
    r.y = (acc[i][1] - mn.y) * inv1 + bt.y;
    r.z = (acc[i][2] - mn.z) * inv2 + bt.z;
    r.w = (acc[i][3] - mn.w) * inv3 + bt.w;
    *(float4*)&dstb[(size_t)row * HDIM + col] = r;
  }
}

// ---------------- Phase 2: persistent recurrence ----------------
// 128 blocks = 16 batches x 8 groups. Block (b,g) owns h indices [g*64,(g+1)*64)
// and U rows {g*64..g*64+63} U {512+g*64..512+g*64+63}, resident in VGPRs.
// Per step: matvec from LDS h, lane-reduce, gate math, write h slice to d_out
// (overwriting its own w_a slot) + exchange buffer, flag barrier (agent scope),
// reload full h. Double-buffered exchange (parity t&1) makes overwrite safe.
__global__ __launch_bounds__(512, 2) void rnn_kernel(
    const float* __restrict__ U,
    float* __restrict__ out,              // w_a in, h out (in place)
    const float* __restrict__ wz,
    float* __restrict__ xbuf,             // [16][2][512]
    int* __restrict__ flags)              // [16][8] stride-16 ints
{
  __shared__ float hcur[512];
  __shared__ float dots[128];
  const int tid = threadIdx.x;
  const int bid = blockIdx.x;
  // group the 8 blocks of a batch on one XCD (bid % 8 congruence); perf hint only
  const int xcd = bid & 7, s = bid >> 3;
  const int b = (xcd << 1) | (s >> 3);
  const int g = s & 7;
  const int g0 = g * 64;
  const int c  = tid & 15;    // col group: cols [c*32, c*32+32)
  const int rg = tid >> 4;    // 0..31: local rows rg*4..rg*4+3

  // persistent U slice: 4 rows x 32 cols = 128 VGPRs
  float4 u[4][8];
#pragma unroll
  for (int i = 0; i < 4; ++i) {
    const int lr = rg * 4 + i;
    const int grow = (lr < 64) ? (g0 + lr) : (HDIM + g0 + (lr - 64));
    const float* up = &U[(size_t)grow * HDIM + c * 32];
#pragma unroll
    for (int q = 0; q < 8; ++q) u[i][q] = *(const float4*)&up[q * 4];
  }

  hcur[tid] = 0.f;
  if (tid >= 64 && tid < 512) { /* nothing */ }
  float wa = 0.f, wzv = 0.f;
  const size_t obase = (size_t)b * TSTEPS * HDIM;
  if (tid < 64) {
    wa  = out[obase + g0 + tid];
    wzv = wz [obase + g0 + tid];
  }
  int* flagp = flags + b * 8 * 16;
  __syncthreads();

  for (int t = 0; t < TSTEPS; ++t) {
    // ---- matvec: dots[r] = U_row_r . h ----
    float4 hv[8];
    const float* hb = &hcur[c * 32];
#pragma unroll
    for (int q = 0; q < 8; ++q) hv[q] = *(const float4*)&hb[q * 4];
    float a0 = 0.f, a1 = 0.f, a2 = 0.f, a3 = 0.f;
#pragma unroll
    for (int q = 0; q < 8; ++q) {
      a0 += u[0][q].x * hv[q].x + u[0][q].y * hv[q].y + u[0][q].z * hv[q].z + u[0][q].w * hv[q].w;
      a1 += u[1][q].x * hv[q].x + u[1][q].y * hv[q].y + u[1][q].z * hv[q].z + u[1][q].w * hv[q].w;
      a2 += u[2][q].x * hv[q].x + u[2][q].y * hv[q].y + u[2][q].z * hv[q].z + u[2][q].w * hv[q].w;
      a3 += u[3][q].x * hv[q].x + u[3][q].y * hv[q].y + u[3][q].z * hv[q].z + u[3][q].w * hv[q].w;
    }
#pragma unroll
    for (int s2 = 1; s2 < 16; s2 <<= 1) {
      a0 += __shfl_xor(a0, s2);
      a1 += __shfl_xor(a1, s2);
      a2 += __shfl_xor(a2, s2);
      a3 += __shfl_xor(a3, s2);
    }
    if (c == 0) {
      dots[rg * 4 + 0] = a0;
      dots[rg * 4 + 1] = a1;
      dots[rg * 4 + 2] = a2;
      dots[rg * 4 + 3] = a3;
    }
    __syncthreads();

    // ---- gates + h update (wave 0) ----
    float* xb = xbuf + ((size_t)b * 2 + (t & 1)) * 512;
    if (tid < 64) {
      const float a  = wa  + dots[tid];
      const float zg = wzv + dots[64 + tid];
      const float z  = 1.f / (1.f + expf(-zg));
      const float hc = fmaxf(a, 0.f);
      const float ho = hcur[g0 + tid];
      const float hn = z * ho + (1.f - z) * hc;
      out[obase + (size_t)t * HDIM + g0 + tid] = hn;   // overwrites our w_a slot
      __hip_atomic_store(&xb[g0 + tid], hn, __ATOMIC_RELAXED, __HIP_MEMORY_SCOPE_AGENT);
      if (t + 1 < TSTEPS) {  // prefetch next step's biases (latency hides in barrier)
        wa  = out[obase + (size_t)(t + 1) * HDIM + g0 + tid];
        wzv = wz [obase + (size_t)(t + 1) * HDIM + g0 + tid];
      }
    }
    __syncthreads();   // compiler drains vmcnt(0) before s_barrier -> stores done
    if (tid == 0)
      __hip_atomic_store(&flagp[g * 16], t + 1, __ATOMIC_RELEASE, __HIP_MEMORY_SCOPE_AGENT);
    if (tid < 64) {
      for (;;) {
        const int f = (tid < 8)
            ? __hip_atomic_load(&flagp[tid * 16], __ATOMIC_RELAXED, __HIP_MEMORY_SCOPE_AGENT)
            : (t + 1);
        if (__all(f >= t + 1)) break;
      }
      __threadfence();   // acquire: order the exchange reads below
    }
    __syncthreads();
    hcur[tid] = __hip_atomic_load(&xb[tid], __ATOMIC_RELAXED, __HIP_MEMORY_SCOPE_AGENT);
    __syncthreads();
  }
}

extern "C" void kernel_launch(void* const* d_in, const int* in_sizes, int n_in,
                              void* d_out, int out_size, void* d_ws, size_t ws_size,
                              hipStream_t stream) {
  const float* x     = (const float*)d_in[0];
  const float* W     = (const float*)d_in[1];
  const float* U     = (const float*)d_in[2];
  const float* gamma = (const float*)d_in[3];
  const float* beta  = (const float*)d_in[4];
  const float* rmean = (const float*)d_in[5];
  const float* rvar  = (const float*)d_in[6];
  float* out = (float*)d_out;

  const size_t wz_bytes = (size_t)MTOT * HDIM * sizeof(float);   // 65,536,000
  float* wzp  = (float*)d_ws;
  float* xbuf = (float*)((char*)d_ws + wz_bytes);
  int*   flags = (int*)((char*)d_ws + wz_bytes + (size_t)NBATCH * 2 * 512 * sizeof(float));

  hipMemsetAsync(flags, 0, NBATCH * 8 * 16 * sizeof(int), stream);

  dim3 g1(HDIM * 2 / 64, MTOT / 64), b1(256);
  gemm_bn_kernel<<<g1, b1, 0, stream>>>(x, W, gamma, beta, rmean, rvar, out, wzp);
  rnn_kernel<<<dim3(128), dim3(512), 0, stream>>>(U, out, wzp, xbuf, flags);
}